// Round 5
// baseline (838.447 us; speedup 1.0000x reference)
//
#include <hip/hip_runtime.h>
#include <hip/hip_bf16.h>
#include <math.h>

// Shapes: x [128,20000,1] f32; rows/cols [640000] i32; vals [640000] f32
// W_gc [20,10]; b_gc [10]; W_fc [200000,10]; b_fc [10]; out [128,10] f32.

#define NF 10
#define KCHEB 20
#define BCG 32                     // batch elements per XCD chunk
#define COFF (KCHEB * BCG)         // 640: element stride between nodes in Xt
#define DBINS 1024                 // degree-sort bins
#define CTILE 2048                 // csr entries staged per LDS chunk (16 KB)

typedef int   v4i __attribute__((ext_vector_type(4)));
typedef float v4f __attribute__((ext_vector_type(4)));

// ---------------- CSR build (degree-sorted) ----------------

__global__ void init_kernel(int* counts, float* h_part, int* dhist, int N, int H) {
    int i = blockIdx.x * blockDim.x + threadIdx.x;
    if (i < N) counts[i] = 0;
    if (i < H) h_part[i] = 0.f;
    if (i < DBINS) dhist[i] = 0;
}

__global__ void hist_kernel(const int* __restrict__ rows, int* __restrict__ counts, int E) {
    int e = blockIdx.x * blockDim.x + threadIdx.x;
    if (e < E) atomicAdd(&counts[rows[e]], 1);
}

__global__ void deg_hist_kernel(const int* __restrict__ counts, int* __restrict__ dhist, int N) {
    int n = blockIdx.x * blockDim.x + threadIdx.x;
    if (n < N) atomicAdd(&dhist[min(counts[n], DBINS - 1)], 1);
}

__global__ void dscan_kernel(const int* __restrict__ dhist, int* __restrict__ dcursor) {
    __shared__ int sh[DBINS];
    int t = threadIdx.x;
    sh[t] = dhist[t];
    __syncthreads();
    for (int off = 1; off < DBINS; off <<= 1) {
        int v = (t >= off) ? sh[t - off] : 0;
        __syncthreads();
        sh[t] += v;
        __syncthreads();
    }
    dcursor[t] = (t == 0) ? 0 : sh[t - 1];   // exclusive prefix
}

__global__ void perm_kernel(const int* __restrict__ counts, int* __restrict__ dcursor,
                            int* __restrict__ perm, int* __restrict__ invperm, int N) {
    int n = blockIdx.x * blockDim.x + threadIdx.x;
    if (n >= N) return;
    int bin = min(counts[n], DBINS - 1);
    int p = atomicAdd(&dcursor[bin], 1);
    perm[p] = n;
    invperm[n] = p;
}

#define SCAN_THREADS 1024
// scan of counts[perm[r]] -> row_start2 (sorted-row CSR offsets) + cursor2
__global__ void scan_kernel(const int* __restrict__ counts, const int* __restrict__ perm,
                            int* __restrict__ row_start, int* __restrict__ cursor, int N) {
    __shared__ int sh[SCAN_THREADS];
    int t = threadIdx.x;
    int CH = (N + SCAN_THREADS - 1) / SCAN_THREADS;
    int base = t * CH;
    int sum = 0;
    for (int i = 0; i < CH; ++i) {
        int idx = base + i;
        sum += (idx < N) ? counts[perm[idx]] : 0;
    }
    sh[t] = sum;
    __syncthreads();
    for (int off = 1; off < SCAN_THREADS; off <<= 1) {
        int v = (t >= off) ? sh[t - off] : 0;
        __syncthreads();
        sh[t] += v;
        __syncthreads();
    }
    int run = (t == 0) ? 0 : sh[t - 1];
    for (int i = 0; i < CH; ++i) {
        int idx = base + i;
        if (idx < N) {
            int v = counts[perm[idx]];
            row_start[idx] = run;
            cursor[idx] = run;
            run += v;
        }
    }
    if (t == SCAN_THREADS - 1) row_start[N] = run;
}

// csr[p] = (col*COFF, bits(val)), stored in degree-sorted row order
__global__ void scatter_kernel(const int* __restrict__ rows, const int* __restrict__ cols,
                               const float* __restrict__ vals, const int* __restrict__ invperm,
                               int* __restrict__ cursor,
                               int2* __restrict__ csr, int E) {
    int e = blockIdx.x * blockDim.x + threadIdx.x;
    if (e >= E) return;
    int r = invperm[rows[e]];
    int p = atomicAdd(&cursor[r], 1);
    csr[p] = make_int2(cols[e] * COFF, __float_as_int(vals[e]));
}

// ---------------- T0 fill (tiled transpose) ----------------
// Xt layout: element (g, n, k, bb) at ((g*N + n)*COFF + k*BCG + bb)

__global__ void transpose_kernel(const float* __restrict__ x, float* __restrict__ Xt,
                                 int N, int ntiles, int b0s) {
    __shared__ float tile[BCG][65];
    int tid = threadIdx.x;
    int g = blockIdx.x / ntiles;
    int ti = blockIdx.x - g * ntiles;
    int n0 = ti * 64;
#pragma unroll
    for (int p = 0; p < 8; ++p) {
        int idx = p * 256 + tid;
        int row = idx >> 6;
        int col = idx & 63;
        if (n0 + col < N)
            tile[row][col] = x[(size_t)(b0s + g * BCG + row) * N + n0 + col];
    }
    __syncthreads();
#pragma unroll
    for (int p = 0; p < 8; ++p) {
        int idx = p * 256 + tid;
        int nloc = idx >> 5;
        int bb = idx & (BCG - 1);
        int n = n0 + nloc;
        if (n < N)
            Xt[((size_t)g * N + n) * COFF + bb] = tile[bb][nloc];
    }
}

// ---------------- SpMM step ----------------
// Rows processed in degree-sorted order (equal-degree waves, contiguous CSR span
// per block staged in LDS via nt loads). Gathers stay in L2; kPrev/kOut are nt.

__global__ __launch_bounds__(256)
void spmm_kernel(float* __restrict__ Xt,
                 const int* __restrict__ row_start2, const int* __restrict__ perm,
                 const int2* __restrict__ csr,
                 int N, int xpcShift, int subsPerChunk,
                 int kIn, int kPrev, int kOut, float alpha, float beta) {
    __shared__ int2 sEdge[CTILE];
    int xcd = blockIdx.x & 7;
    int chunk = xcd >> xpcShift;
    int xpcMask = (1 << xpcShift) - 1;
    int sub = (blockIdx.x >> 3) * (1 << xpcShift) + (xcd & xpcMask);
    if (sub >= subsPerChunk) return;
    int tid = threadIdx.x;
    int ln = tid >> 3;             // row slot 0..31 within block
    int bq = tid & 7;              // float4 lane within batch chunk
    int r0 = sub * 32;
    int rowsInBlk = (N - r0 < 32) ? (N - r0) : 32;
    int r = r0 + ln;
    bool active = (r < N);
    int sblk = row_start2[r0];
    int eblk = row_start2[r0 + rowsInBlk];
    int s = 0, e = 0, n = 0;
    if (active) { s = row_start2[r]; e = row_start2[r + 1]; n = perm[r]; }

    float* base = Xt + (size_t)chunk * N * COFF;
    int koff = kIn * BCG + bq * 4;
    float4 a0 = make_float4(0.f, 0.f, 0.f, 0.f);
    float4 a1 = make_float4(0.f, 0.f, 0.f, 0.f);

    for (int cs = sblk; cs < eblk; cs += CTILE) {
        int cnt = (eblk - cs < CTILE) ? (eblk - cs) : CTILE;
        // cooperative nt staging: 256 thr x 2 entries (16B) per pass
        for (int o = tid * 2; o < cnt; o += 512) {
            if (o + 1 < cnt) {
                v4i w = __builtin_nontemporal_load((const v4i*)(csr + cs + o));
                *(v4i*)(sEdge + o) = w;
            } else {
                long long w = __builtin_nontemporal_load((const long long*)(csr + cs + o));
                *(long long*)(sEdge + o) = w;
            }
        }
        __syncthreads();
        if (active) {
            int i0 = (s > cs ? s : cs) - cs;
            int hi = (e < cs + cnt ? e : cs + cnt);
            int i1 = (hi > cs) ? hi - cs : i0;
            int i = i0;
            for (; i + 4 <= i1; i += 4) {
                int2 p0 = sEdge[i], p1 = sEdge[i + 1], p2 = sEdge[i + 2], p3 = sEdge[i + 3];
                const float4 t0 = *(const float4*)(base + p0.x + koff);
                const float4 t1 = *(const float4*)(base + p1.x + koff);
                const float4 t2 = *(const float4*)(base + p2.x + koff);
                const float4 t3 = *(const float4*)(base + p3.x + koff);
                float v0 = __int_as_float(p0.y), v1 = __int_as_float(p1.y);
                float v2 = __int_as_float(p2.y), v3 = __int_as_float(p3.y);
                a0.x += v0 * t0.x; a0.y += v0 * t0.y; a0.z += v0 * t0.z; a0.w += v0 * t0.w;
                a1.x += v1 * t1.x; a1.y += v1 * t1.y; a1.z += v1 * t1.z; a1.w += v1 * t1.w;
                a0.x += v2 * t2.x; a0.y += v2 * t2.y; a0.z += v2 * t2.z; a0.w += v2 * t2.w;
                a1.x += v3 * t3.x; a1.y += v3 * t3.y; a1.z += v3 * t3.z; a1.w += v3 * t3.w;
            }
            for (; i < i1; ++i) {
                int2 p0 = sEdge[i];
                const float4 t0 = *(const float4*)(base + p0.x + koff);
                float v0 = __int_as_float(p0.y);
                a0.x += v0 * t0.x; a0.y += v0 * t0.y; a0.z += v0 * t0.z; a0.w += v0 * t0.w;
            }
        }
        __syncthreads();
    }
    if (!active) return;

    float4 acc;
    acc.x = alpha * (a0.x + a1.x); acc.y = alpha * (a0.y + a1.y);
    acc.z = alpha * (a0.z + a1.z); acc.w = alpha * (a0.w + a1.w);
    size_t nbase = (size_t)n * COFF + bq * 4;
    if (beta != 0.f) {
        v4f pv = __builtin_nontemporal_load((const v4f*)(base + nbase + kPrev * BCG));
        acc.x += beta * pv.x; acc.y += beta * pv.y;
        acc.z += beta * pv.z; acc.w += beta * pv.w;
    }
    v4f o4 = {acc.x, acc.y, acc.z, acc.w};
    __builtin_nontemporal_store(o4, (v4f*)(base + nbase + kOut * BCG));
}

// ---------------- Fused projection + FC partial ----------------

__global__ __launch_bounds__(256, 4)
void proj_fc_kernel(const float* __restrict__ Xt,
                    const float* __restrict__ W_gc,
                    const float* __restrict__ b_gc,
                    const float* __restrict__ W_fc,
                    float* __restrict__ h_part,
                    int N, int b0s, int G) {
    __shared__ float sWg[KCHEB * NF];
    __shared__ float sbg[NF];
    __shared__ float sRed[BCG * NF];
    __shared__ float sWf[8 * NF * NF];
    int tid = threadIdx.x;
    if (tid < KCHEB * NF) sWg[tid] = W_gc[tid];
    if (tid < NF) sbg[tid] = b_gc[tid];
    for (int i = tid; i < BCG * NF; i += 256) sRed[i] = 0.f;
    __syncthreads();

    int g = blockIdx.x % G;
    int bidx = blockIdx.x / G;
    int nblk = gridDim.x / G;

    int bb = tid & (BCG - 1);
    int ln = tid >> 5;

    float h_loc[NF];
#pragma unroll
    for (int f = 0; f < NF; ++f) h_loc[f] = 0.f;

    const float* chunkBase = Xt + (size_t)g * N * COFF;
    int ngroups = (N + 7) / 8;
    for (int grp = bidx; grp < ngroups; grp += nblk) {
        int n0 = grp * 8;
        int lim = (N - n0 < 8 ? N - n0 : 8) * (NF * NF);
        int o = tid * 4;
        if (o < lim) {
            float4 w = *(const float4*)(W_fc + (size_t)n0 * (NF * NF) + o);
            *(float4*)(sWf + o) = w;
        }
        __syncthreads();

        int n = n0 + ln;
        if (n < N) {
            float xt[KCHEB];
            const float* xp = chunkBase + (size_t)n * COFF + bb;
#pragma unroll
            for (int k = 0; k < KCHEB; ++k) xt[k] = xp[k * BCG];
            const float* wrow = sWf + ln * (NF * NF);
#pragma unroll
            for (int j = 0; j < NF; ++j) {
                float gc = sbg[j];
#pragma unroll
                for (int k = 0; k < KCHEB; ++k) gc += xt[k] * sWg[k * NF + j];
                gc = fmaxf(gc, 0.f);
#pragma unroll
                for (int f = 0; f < NF; ++f) h_loc[f] += gc * wrow[j * NF + f];
            }
        }
        __syncthreads();
    }
#pragma unroll
    for (int f = 0; f < NF; ++f) atomicAdd(&sRed[bb * NF + f], h_loc[f]);
    __syncthreads();
    for (int i = tid; i < BCG * NF; i += 256)
        atomicAdd(&h_part[(size_t)(b0s + g * BCG) * NF + i], sRed[i]);
}

// ---------------- Bias + ReLU + softmax ----------------

__global__ void softmax_kernel(const float* __restrict__ h_part, const float* __restrict__ b_fc,
                               float* __restrict__ out, int B) {
    int b = blockIdx.x * blockDim.x + threadIdx.x;
    if (b >= B) return;
    float v[NF];
    float m = -1e30f;
#pragma unroll
    for (int f = 0; f < NF; ++f) {
        float t = fmaxf(h_part[b * NF + f] + b_fc[f], 0.f);
        v[f] = t;
        m = fmaxf(m, t);
    }
    float s = 0.f;
#pragma unroll
    for (int f = 0; f < NF; ++f) { v[f] = expf(v[f] - m); s += v[f]; }
    float inv = 1.f / s;
#pragma unroll
    for (int f = 0; f < NF; ++f) out[b * NF + f] = v[f] * inv;
}

// ---------------- launch ----------------

extern "C" void kernel_launch(void* const* d_in, const int* in_sizes, int n_in,
                              void* d_out, int out_size, void* d_ws, size_t ws_size,
                              hipStream_t stream) {
    const float* x    = (const float*)d_in[0];
    const int*   rows = (const int*)d_in[1];
    const int*   cols = (const int*)d_in[2];
    const float* vals = (const float*)d_in[3];
    const float* W_gc = (const float*)d_in[4];
    const float* b_gc = (const float*)d_in[5];
    const float* W_fc = (const float*)d_in[6];
    const float* b_fc = (const float*)d_in[7];
    float* out = (float*)d_out;

    const int E = in_sizes[1];
    const int N = in_sizes[6] / (NF * NF);
    const int B = in_sizes[0] / N;

    // ---- workspace carve ----
    char* p = (char*)d_ws;
    int* counts    = (int*)p;   p += sizeof(int) * (size_t)N;
    int* row_start = (int*)p;   p += sizeof(int) * (size_t)(N + 1);
    int* cursor    = (int*)p;   p += sizeof(int) * (size_t)N;
    int* dhist     = (int*)p;   p += sizeof(int) * (size_t)DBINS;
    int* dcursor   = (int*)p;   p += sizeof(int) * (size_t)DBINS;
    int* perm      = (int*)p;   p += sizeof(int) * (size_t)N;
    int* invperm   = (int*)p;   p += sizeof(int) * (size_t)N;
    p = (char*)(((size_t)p + 15) & ~(size_t)15);
    int2* csr      = (int2*)p;  p += sizeof(int2) * (size_t)E;
    float* h_part  = (float*)p; p += sizeof(float) * (size_t)B * NF;
    size_t fixed = (size_t)(p - (char*)d_ws);
    fixed = (fixed + 255) & ~(size_t)255;
    float* Xt = (float*)((char*)d_ws + fixed);

    // choose G chunks of 32 resident at once (G in {4,2,1})
    size_t perChunk = (size_t)N * COFF * sizeof(float);  // 51.2 MB
    int G = (B >= 4 * BCG) ? 4 : (B >= 2 * BCG ? 2 : 1);
    while (G > 1 && fixed + (size_t)G * perChunk > ws_size) G >>= 1;
    int xpcShift = (G == 4) ? 1 : (G == 2 ? 2 : 3);
    int BT = G * BCG;
    int nsc = B / BT;

    // ---- degree-sorted CSR build ----
    {
        int H = B * NF;
        int cov = (N > H) ? N : H;
        if (cov < DBINS) cov = DBINS;
        init_kernel<<<(cov + 255) / 256, 256, 0, stream>>>(counts, h_part, dhist, N, H);
        hist_kernel<<<(E + 255) / 256, 256, 0, stream>>>(rows, counts, E);
        deg_hist_kernel<<<(N + 255) / 256, 256, 0, stream>>>(counts, dhist, N);
        dscan_kernel<<<1, DBINS, 0, stream>>>(dhist, dcursor);
        perm_kernel<<<(N + 255) / 256, 256, 0, stream>>>(counts, dcursor, perm, invperm, N);
        scan_kernel<<<1, SCAN_THREADS, 0, stream>>>(counts, perm, row_start, cursor, N);
        scatter_kernel<<<(E + 255) / 256, 256, 0, stream>>>(rows, cols, vals, invperm,
                                                            cursor, csr, E);
    }

    int ntiles = (N + 63) / 64;
    int subsPerChunk = (N + 31) / 32;
    int xpc = 1 << xpcShift;
    int gridSpmm = 8 * ((subsPerChunk + xpc - 1) / xpc);

    for (int c = 0; c < nsc; ++c) {
        int b0s = c * BT;
        transpose_kernel<<<G * ntiles, 256, 0, stream>>>(x, Xt, N, ntiles, b0s);
        for (int k = 1; k < KCHEB; ++k) {
            float alpha = (k == 1) ? 1.f : 2.f;
            float beta  = (k == 1) ? 0.f : -1.f;
            spmm_kernel<<<gridSpmm, 256, 0, stream>>>(
                Xt, row_start, perm, csr, N, xpcShift, subsPerChunk,
                k - 1, k - 2 < 0 ? 0 : k - 2, k, alpha, beta);
        }
        proj_fc_kernel<<<2048, 256, 0, stream>>>(Xt, W_gc, b_gc, W_fc, h_part, N, b0s, G);
    }

    softmax_kernel<<<1, 128, 0, stream>>>(h_part, b_fc, out, B);
}